// Round 2
// baseline (833.001 us; speedup 1.0000x reference)
//
#include <hip/hip_runtime.h>

// B=2,S=2048 -> T=4096 tokens, D=1024, F=4096, E=8; top_k on device.
// fp32 I/O; bf16 MFMA compute (fp32 accumulate).
// R7: 256x256-tile BK=32 8-wave GEMMs with 3-buffer counted-vmcnt pipeline
// (T3+T4), T2 LDS swizzle (inverse-swz source + swz read), T5 setprio.
// Work list at 256-row granularity. gemm2 split-K x2 + atomic epilogue.
#define T_TOK 4096
#define DIM   1024
#define FDIM  4096
#define NEXP  8

typedef __bf16 bf16x8 __attribute__((ext_vector_type(8)));
typedef __bf16 bf16x4 __attribute__((ext_vector_type(4)));
typedef float  f32x4  __attribute__((ext_vector_type(4)));

__device__ __forceinline__ void glds16(const void* g, void* l) {
    __builtin_amdgcn_global_load_lds(
        (const __attribute__((address_space(1))) void*)g,
        (__attribute__((address_space(3))) void*)l, 16, 0, 0);
}

// Bijective XCD-chunking swizzle (m204).
__device__ __forceinline__ int xcd_swz(int phys, int total) {
    int q = total >> 3, r = total & 7;
    int x = phys & 7, i = phys >> 3;
    return (x < r ? x * (q + 1) : r * (q + 1) + (x - r) * q) + i;
}

// ---------------------------------------------------------------------------
// Router (+ x->bf16 convert): one wave per token.
// ---------------------------------------------------------------------------
__global__ __launch_bounds__(64)
void moe_router(const float* __restrict__ x,
                const float* __restrict__ gw,
                const float* __restrict__ gb,
                const int*   __restrict__ topk_p,
                int*   __restrict__ counts,
                int*   __restrict__ bucket,
                float* __restrict__ bweight,
                __bf16* __restrict__ xb) {
    const int t = blockIdx.x;
    const int lane = threadIdx.x;
    float part[NEXP];
#pragma unroll
    for (int e = 0; e < NEXP; ++e) part[e] = 0.f;
    const float* xrow = x + (size_t)t * DIM;
    __bf16* xbrow = xb + (size_t)t * DIM;
#pragma unroll
    for (int r = 0; r < 4; ++r) {
        int c = r * 256 + lane * 4;
        float4 v = *(const float4*)&xrow[c];
        bf16x4 o; o[0]=(__bf16)v.x; o[1]=(__bf16)v.y; o[2]=(__bf16)v.z; o[3]=(__bf16)v.w;
        *(bf16x4*)&xbrow[c] = o;
#pragma unroll
        for (int e = 0; e < NEXP; ++e) {
            float4 g = *(const float4*)&gw[e * DIM + c];
            part[e] += v.x*g.x + v.y*g.y + v.z*g.z + v.w*g.w;
        }
    }
#pragma unroll
    for (int off = 32; off > 0; off >>= 1) {
#pragma unroll
        for (int e = 0; e < NEXP; ++e) part[e] += __shfl_xor(part[e], off);
    }
    if (lane == 0) {
        int k = topk_p[0];
        if (k < 1) k = 1;
        if (k > NEXP) k = NEXP;
        float p[NEXP];
        float mx = -1e30f;
#pragma unroll
        for (int e = 0; e < NEXP; ++e) {
            p[e] = part[e] + gb[e];
            mx = fmaxf(mx, p[e]);
        }
#pragma unroll
        for (int e = 0; e < NEXP; ++e) p[e] = __expf(p[e] - mx);
        bool used[NEXP];
#pragma unroll
        for (int e = 0; e < NEXP; ++e) used[e] = false;
        int sel[NEXP]; float selp[NEXP]; float wsum = 0.f;
        for (int j = 0; j < k; ++j) {
            int best = 0; float bv = -1.f;
            for (int e = 0; e < NEXP; ++e)
                if (!used[e] && p[e] > bv) { bv = p[e]; best = e; }  // ties->low idx
            used[best] = true; sel[j] = best; selp[j] = bv; wsum += bv;
        }
        for (int j = 0; j < k; ++j) {
            int e = sel[j];
            int pos = atomicAdd(&counts[e], 1);
            bucket[e * T_TOK + pos]  = t;
            bweight[e * T_TOK + pos] = selp[j] / wsum;
        }
    }
}

// Per-expert transpose+convert: in [z][R][C] fp32 -> out [z][C][R] bf16.
__global__ __launch_bounds__(256)
void transpose_cvt(const float* __restrict__ in, __bf16* __restrict__ out,
                   int R, int C) {
    const size_t zo = (size_t)blockIdx.z * R * C;
    in += zo; out += zo;
    __shared__ float ts[64][65];
    const int c0 = blockIdx.x * 64, r0 = blockIdx.y * 64;
    const int t = threadIdx.x;
    const int rr = t >> 2, cc4 = (t & 3) * 16;
    const float* src = in + (size_t)(r0 + rr) * C + c0 + cc4;
#pragma unroll
    for (int i = 0; i < 4; ++i) {
        float4 v = *(const float4*)(src + i * 4);
        ts[rr][cc4 + i*4 + 0] = v.x; ts[rr][cc4 + i*4 + 1] = v.y;
        ts[rr][cc4 + i*4 + 2] = v.z; ts[rr][cc4 + i*4 + 3] = v.w;
    }
    __syncthreads();
    const int oc = rr, orc = cc4;
    bf16x8 o0, o1;
#pragma unroll
    for (int i = 0; i < 8; ++i) o0[i] = (__bf16)ts[orc + i][oc];
#pragma unroll
    for (int i = 0; i < 8; ++i) o1[i] = (__bf16)ts[orc + 8 + i][oc];
    __bf16* dst = out + (size_t)(c0 + oc) * R + r0 + orc;
    *(bf16x8*)dst = o0;
    *(bf16x8*)(dst + 8) = o1;
}

// ---------------------------------------------------------------------------
// Work list: (e, tile256) entries; hdr[0]=n, entries at hdr+8.
// ---------------------------------------------------------------------------
__global__ __launch_bounds__(64)
void build_work(const int* __restrict__ counts, int* __restrict__ hdr) {
    __shared__ int off1[NEXP + 1];
    const int lane = threadIdx.x;
    if (lane == 0) {
        int a = 0;
        for (int e = 0; e < NEXP; ++e) {
            off1[e] = a;
            a += (counts[e] + 255) >> 8;
        }
        off1[NEXP] = a;
        hdr[0] = a;
    }
    __syncthreads();
    for (int e = 0; e < NEXP; ++e) {
        int n1 = off1[e + 1] - off1[e];
        for (int j = lane; j < n1; j += 64) hdr[8 + off1[e] + j] = (e << 16) | j;
    }
}

// ---------------------------------------------------------------------------
// Shared GEMM geometry (both gemms):
//   tile 256x256, BK=32, 512 threads = 8 waves as 2(M) x 4(N).
//   LDS: 3 buffers x (A[256][32] 16KB | B[256][32] 16KB) = 96KB.
//   Row = 64B; T2 swizzle: 16B-slot s stored at s ^ ((row>>1)&3).
//   Staging (global_load_lds writes LINEARLY at lane*16): source column
//   chunk is inverse-swizzled: src_chunk = (tid&3) ^ ((tid>>3)&3).
//   Pipeline: stage t+2, s_waitcnt vmcnt(8) (tile t landed, 8 in flight),
//   s_barrier, 12x ds_read_b128 + 32 MFMA (setprio), s_barrier.
// ---------------------------------------------------------------------------

// ---------------------------------------------------------------------------
// GEMM1: H[e,pos,f] = silu( xb[tok].W1T[e][f][:] + b1[e][f] )
// ---------------------------------------------------------------------------
__global__ __launch_bounds__(512, 2)
void moe_gemm1(const __bf16* __restrict__ xb,
               const __bf16* __restrict__ w1t,   // [E][F][D]
               const float*  __restrict__ b1,
               const int*    __restrict__ counts,
               const int*    __restrict__ bucket,
               const int*    __restrict__ hdr,
               __bf16* __restrict__ H) {
    __shared__ __align__(16) char sb[3 * 32768];   // 96KB pipeline buffers
    __shared__ int tok_s[256];
    const int tid = threadIdx.x;
    const int wave = tid >> 6, lane = tid & 63;
    const int wm = wave & 1, wn = wave >> 1;        // 2 x 4 wave grid
    const int quad = lane >> 4, l15 = lane & 15;
    const int lrow = lane >> 2;
    // staging: thread covers row rr (and rr+128) of the tile, 16B slot tid&3
    const int rr  = tid >> 2;
    const int srh = ((tid & 3) ^ ((tid >> 3) & 3)) * 8;   // inverse-swz src elems
    // fragment read: swizzled 16B slot for (quad, row l15)
    const int swz16 = (((lane >> 4) ^ ((lane >> 1) & 3)) << 4);
    const int aoff = (wm * 128 + l15) * 64 + swz16;
    const int boff = (wn * 64  + l15) * 64 + swz16;

    const int NT = DIM / 32;   // 32 K-tiles
    const int n1 = hdr[0];
    const int total = n1 * (FDIM / 256);
    for (int phys = blockIdx.x; phys < total; phys += gridDim.x) {
        const int u = xcd_swz(phys, total);
        const int entry = hdr[8 + (u % n1)];
        const int e = entry >> 16, tile = entry & 0xffff;
        const int nb = (u / n1) * 256;
        const int cnt = counts[e];
        for (int r = tid; r < 256; r += 512) {
            int rw = tile * 256 + r;
            if (rw >= cnt) rw = cnt - 1;
            tok_s[r] = bucket[e * T_TOK + rw];
        }
        __syncthreads();   // also drains vmcnt to 0 for clean counting

        const __bf16* pa0 = xb + (size_t)tok_s[rr]       * DIM + srh;
        const __bf16* pa1 = xb + (size_t)tok_s[rr + 128] * DIM + srh;
        const __bf16* pb0 = w1t + ((size_t)e * FDIM + nb + rr) * DIM + srh;
        const __bf16* pb1 = pb0 + (size_t)128 * DIM;

        f32x4 acc[8][4];
#pragma unroll
        for (int i = 0; i < 8; ++i)
#pragma unroll
            for (int j = 0; j < 4; ++j) acc[i][j] = (f32x4){0.f,0.f,0.f,0.f};

        // prologue: stage tiles 0,1 into buffers 0,1 (4 glds16 each)
#pragma unroll
        for (int p = 0; p < 2; ++p) {
            char* db = sb + p * 32768;
            const int ko = p * 32;
            glds16(pa0 + ko, db + wave * 1024);
            glds16(pa1 + ko, db + 8192 + wave * 1024);
            glds16(pb0 + ko, db + 16384 + wave * 1024);
            glds16(pb1 + ko, db + 24576 + wave * 1024);
        }

        int bc = 0, bn = 2;
#pragma unroll 1
        for (int t = 0; t < NT; ++t) {
            if (t + 2 < NT) {
                char* db = sb + bn * 32768;
                const int ko = (t + 2) * 32;
                glds16(pa0 + ko, db + wave * 1024);
                glds16(pa1 + ko, db + 8192 + wave * 1024);
                glds16(pb0 + ko, db + 16384 + wave * 1024);
                glds16(pb1 + ko, db + 24576 + wave * 1024);
                asm volatile("s_waitcnt vmcnt(8)" ::: "memory");
            } else if (t + 2 == NT) {
                asm volatile("s_waitcnt vmcnt(4)" ::: "memory");
            } else {
                asm volatile("s_waitcnt vmcnt(0)" ::: "memory");
            }
            __builtin_amdgcn_s_barrier();
            asm volatile("" ::: "memory");

            const char* Ab = sb + bc * 32768;
            const char* Bb = Ab + 16384;
            bf16x8 af[8], bfr[4];
#pragma unroll
            for (int i = 0; i < 8; ++i)
                af[i] = *(const bf16x8*)(Ab + aoff + i * 1024);
#pragma unroll
            for (int j = 0; j < 4; ++j)
                bfr[j] = *(const bf16x8*)(Bb + boff + j * 1024);
            __builtin_amdgcn_s_setprio(1);
#pragma unroll
            for (int i = 0; i < 8; ++i)
#pragma unroll
                for (int j = 0; j < 4; ++j)
                    acc[i][j] = __builtin_amdgcn_mfma_f32_16x16x32_bf16(
                        af[i], bfr[j], acc[i][j], 0, 0, 0);
            __builtin_amdgcn_s_setprio(0);

            asm volatile("" ::: "memory");
            __builtin_amdgcn_s_barrier();
            bc = (bc == 2) ? 0 : bc + 1;
            bn = (bn == 2) ? 0 : bn + 1;
        }

        // Epilogue: wave-private LDS transpose (stride 72, 16B-aligned)
        // -> b128 H stores. All compute done (final barrier above).
        __bf16* stg = (__bf16*)(sb + wave * 2304);
        const float* b1e = b1 + e * FDIM + nb + wn * 64;
#pragma unroll
        for (int i = 0; i < 8; ++i) {
#pragma unroll
            for (int j = 0; j < 4; ++j) {
                float bias = b1e[j * 16 + l15];
#pragma unroll
                for (int r = 0; r < 4; ++r) {
                    float v = acc[i][j][r] + bias;
                    float s = v / (1.f + __expf(-v));   // silu
                    stg[(quad*4 + r) * 72 + j*16 + l15] = (__bf16)s;
                }
            }
            int prow = tile * 256 + wm * 128 + i * 16 + lrow;
            if (prow < cnt) {
                bf16x8 v0 = *(const bf16x8*)&stg[lrow * 72 + (lane & 3) * 16];
                bf16x8 v1 = *(const bf16x8*)&stg[lrow * 72 + (lane & 3) * 16 + 8];
                __bf16* dst = H + (size_t)(e * T_TOK + prow) * FDIM
                              + nb + wn * 64 + (lane & 3) * 16;
                *(bf16x8*)dst = v0;
                *(bf16x8*)(dst + 8) = v1;
            }
        }
        __syncthreads();   // protect smem/tok_s before next unit
    }
}

// ---------------------------------------------------------------------------
// GEMM2: out[tok,d] += w * ( H[e,pos,:].W2T[e][d][:] + b2[e][d] )
// split-K x2 (each block reduces FDIM/2 = 2048).
// ---------------------------------------------------------------------------
#define KSPLIT 2
#define KHALF  (FDIM / KSPLIT)

__global__ __launch_bounds__(512, 2)
void moe_gemm2(const __bf16* __restrict__ H,
               const __bf16* __restrict__ w2t,   // [E][D][F]
               const float*  __restrict__ b2,
               const int*    __restrict__ counts,
               const int*    __restrict__ bucket,
               const float*  __restrict__ bweight,
               const int*    __restrict__ hdr,
               float* __restrict__ out) {
    __shared__ __align__(16) char sb[3 * 32768];
    __shared__ int   tok_s[256];
    __shared__ float w_s[256];
    const int tid = threadIdx.x;
    const int wave = tid >> 6, lane = tid & 63;
    const int wm = wave & 1, wn = wave >> 1;
    const int quad = lane >> 4, l15 = lane & 15;
    const int rr  = tid >> 2;
    const int srh = ((tid & 3) ^ ((tid >> 3) & 3)) * 8;
    const int swz16 = (((lane >> 4) ^ ((lane >> 1) & 3)) << 4);
    const int aoff = (wm * 128 + l15) * 64 + swz16;
    const int boff = (wn * 64  + l15) * 64 + swz16;

    const int NT = KHALF / 32;   // 64 K-tiles
    const int n1 = hdr[0];
    const int total = n1 * (DIM / 256) * KSPLIT;
    for (int phys = blockIdx.x; phys < total; phys += gridDim.x) {
        const int u = xcd_swz(phys, total);
        const int entry = hdr[8 + (u % n1)];
        const int e = entry >> 16, tile = entry & 0xffff;
        const int rest = u / n1;
        const int nb = (rest & 3) * 256;       // DIM/256 = 4 output blocks
        const int kc = rest >> 2;              // split-K chunk: 0 or 1
        const int cnt = counts[e];
        for (int r = tid; r < 256; r += 512) {
            int rw = tile * 256 + r;
            int rc = rw < cnt ? rw : cnt - 1;
            tok_s[r] = bucket[e * T_TOK + rc];
            w_s[r]   = bweight[e * T_TOK + rc];
        }
        __syncthreads();

        const size_t kbase = (size_t)kc * KHALF;
        // A rows (H) are contiguous positions — no gather needed.
        const __bf16* pa0 = H + (size_t)(e * T_TOK + tile * 256 + rr) * FDIM + kbase + srh;
        const __bf16* pa1 = pa0 + (size_t)128 * FDIM;
        const __bf16* pb0 = w2t + ((size_t)e * DIM + nb + rr) * FDIM + kbase + srh;
        const __bf16* pb1 = pb0 + (size_t)128 * FDIM;

        f32x4 acc[8][4];
#pragma unroll
        for (int i = 0; i < 8; ++i)
#pragma unroll
            for (int j = 0; j < 4; ++j) acc[i][j] = (f32x4){0.f,0.f,0.f,0.f};

#pragma unroll
        for (int p = 0; p < 2; ++p) {
            char* db = sb + p * 32768;
            const int ko = p * 32;
            glds16(pa0 + ko, db + wave * 1024);
            glds16(pa1 + ko, db + 8192 + wave * 1024);
            glds16(pb0 + ko, db + 16384 + wave * 1024);
            glds16(pb1 + ko, db + 24576 + wave * 1024);
        }

        int bc = 0, bn = 2;
#pragma unroll 1
        for (int t = 0; t < NT; ++t) {
            if (t + 2 < NT) {
                char* db = sb + bn * 32768;
                const int ko = (t + 2) * 32;
                glds16(pa0 + ko, db + wave * 1024);
                glds16(pa1 + ko, db + 8192 + wave * 1024);
                glds16(pb0 + ko, db + 16384 + wave * 1024);
                glds16(pb1 + ko, db + 24576 + wave * 1024);
                asm volatile("s_waitcnt vmcnt(8)" ::: "memory");
            } else if (t + 2 == NT) {
                asm volatile("s_waitcnt vmcnt(4)" ::: "memory");
            } else {
                asm volatile("s_waitcnt vmcnt(0)" ::: "memory");
            }
            __builtin_amdgcn_s_barrier();
            asm volatile("" ::: "memory");

            const char* Ab = sb + bc * 32768;
            const char* Bb = Ab + 16384;
            bf16x8 af[8], bfr[4];
#pragma unroll
            for (int i = 0; i < 8; ++i)
                af[i] = *(const bf16x8*)(Ab + aoff + i * 1024);
#pragma unroll
            for (int j = 0; j < 4; ++j)
                bfr[j] = *(const bf16x8*)(Bb + boff + j * 1024);
            __builtin_amdgcn_s_setprio(1);
#pragma unroll
            for (int i = 0; i < 8; ++i)
#pragma unroll
                for (int j = 0; j < 4; ++j)
                    acc[i][j] = __builtin_amdgcn_mfma_f32_16x16x32_bf16(
                        af[i], bfr[j], acc[i][j], 0, 0, 0);
            __builtin_amdgcn_s_setprio(0);

            asm volatile("" ::: "memory");
            __builtin_amdgcn_s_barrier();
            bc = (bc == 2) ? 0 : bc + 1;
            bn = (bn == 2) ? 0 : bn + 1;
        }

        float bias[4];
#pragma unroll
        for (int j = 0; j < 4; ++j)
            bias[j] = (kc == 0) ? b2[e * DIM + nb + wn * 64 + j * 16 + l15] : 0.f;
#pragma unroll
        for (int i = 0; i < 8; ++i)
#pragma unroll
            for (int j = 0; j < 4; ++j)
#pragma unroll
                for (int r = 0; r < 4; ++r) {
                    int m = wm * 128 + i * 16 + quad * 4 + r;
                    int prow = tile * 256 + m;
                    if (prow < cnt) {
                        int dc = nb + wn * 64 + j * 16 + l15;
                        float v = acc[i][j][r] + bias[j];
                        atomicAdd(&out[(size_t)tok_s[m] * DIM + dc], w_s[m] * v);
                    }
                }
        __syncthreads();   // protect tok_s/w_s before next unit
    }
}

extern "C" void kernel_launch(void* const* d_in, const int* in_sizes, int n_in,
                              void* d_out, int out_size, void* d_ws, size_t ws_size,
                              hipStream_t stream) {
    const float* x  = (const float*)d_in[0];
    const float* gw = (const float*)d_in[1];
    const float* gb = (const float*)d_in[2];
    const float* w1 = (const float*)d_in[3];
    const float* b1 = (const float*)d_in[4];
    const float* w2 = (const float*)d_in[5];
    const float* b2 = (const float*)d_in[6];
    const int* topk = (const int*)d_in[7];
    float* out = (float*)d_out;

    char* ws = (char*)d_ws;
    size_t off = 0;
    int* counts = (int*)(ws + off);    off += 256;
    int* bucket = (int*)(ws + off);    off += (size_t)NEXP * T_TOK * 4;
    float* bw   = (float*)(ws + off);  off += (size_t)NEXP * T_TOK * 4;
    int* hdr    = (int*)(ws + off);    off += 4096;
    off = (off + 255) & ~(size_t)255;
    __bf16* xb  = (__bf16*)(ws + off); off += (size_t)T_TOK * DIM * 2;        // 8MB
    __bf16* w1t = (__bf16*)(ws + off); off += (size_t)NEXP * DIM * FDIM * 2;  // 64MB
    __bf16* w2t = (__bf16*)(ws + off); off += (size_t)NEXP * FDIM * DIM * 2;  // 64MB
    __bf16* H   = (__bf16*)(ws + off);                                        // 256MB

    hipMemsetAsync(counts, 0, 256, stream);
    hipMemsetAsync(out, 0, (size_t)out_size * 4, stream);

    moe_router<<<T_TOK, 64, 0, stream>>>(x, gw, gb, topk, counts, bucket, bw, xb);
    transpose_cvt<<<dim3(FDIM/64, DIM/64, NEXP), 256, 0, stream>>>(w1, w1t, DIM, FDIM);
    transpose_cvt<<<dim3(DIM/64, FDIM/64, NEXP), 256, 0, stream>>>(w2, w2t, FDIM, DIM);
    build_work<<<1, 64, 0, stream>>>(counts, hdr);

    moe_gemm1<<<256, 512, 0, stream>>>(xb, w1t, b1, counts, bucket, hdr, H);
    moe_gemm2<<<256, 512, 0, stream>>>(H, w2t, b2, counts, bucket, bw, hdr, out);
}

// Round 3
// 771.918 us; speedup vs baseline: 1.0791x; 1.0791x over previous
//
#include <hip/hip_runtime.h>

// B=2,S=2048 -> T=4096 tokens, D=1024, F=4096, E=8; top_k on device.
// fp32 I/O; bf16 MFMA compute (fp32 accumulate).
// R8: counted-vmcnt pipeline made REAL — fragment reads are inline-asm
// ds_read_b128 (compiler can no longer insert vmcnt(0) drains for the
// glds16->ds_read alias), rule-#18 lgkmcnt(0)+sched_barrier(0) before MFMA.
// 4-buffer (depth-3) prefetch, 128KB LDS, 1 block/CU, 256x256 BK=32 8-wave.
#define T_TOK 4096
#define DIM   1024
#define FDIM  4096
#define NEXP  8

typedef __bf16 bf16x8 __attribute__((ext_vector_type(8)));
typedef __bf16 bf16x4 __attribute__((ext_vector_type(4)));
typedef float  f32x4  __attribute__((ext_vector_type(4)));
typedef const __attribute__((address_space(3))) char* lds3;

__device__ __forceinline__ void glds16(const void* g, void* l) {
    __builtin_amdgcn_global_load_lds(
        (const __attribute__((address_space(1))) void*)g,
        (__attribute__((address_space(3))) void*)l, 16, 0, 0);
}

#define DSR(dst, a, imm) \
    asm volatile("ds_read_b128 %0, %1 offset:" #imm : "=v"(dst) : "v"(a) : "memory")

// Bijective XCD-chunking swizzle (m204).
__device__ __forceinline__ int xcd_swz(int phys, int total) {
    int q = total >> 3, r = total & 7;
    int x = phys & 7, i = phys >> 3;
    return (x < r ? x * (q + 1) : r * (q + 1) + (x - r) * q) + i;
}

// ---------------------------------------------------------------------------
// Router (+ x->bf16 convert): one wave per token.
// ---------------------------------------------------------------------------
__global__ __launch_bounds__(64)
void moe_router(const float* __restrict__ x,
                const float* __restrict__ gw,
                const float* __restrict__ gb,
                const int*   __restrict__ topk_p,
                int*   __restrict__ counts,
                int*   __restrict__ bucket,
                float* __restrict__ bweight,
                __bf16* __restrict__ xb) {
    const int t = blockIdx.x;
    const int lane = threadIdx.x;
    float part[NEXP];
#pragma unroll
    for (int e = 0; e < NEXP; ++e) part[e] = 0.f;
    const float* xrow = x + (size_t)t * DIM;
    __bf16* xbrow = xb + (size_t)t * DIM;
#pragma unroll
    for (int r = 0; r < 4; ++r) {
        int c = r * 256 + lane * 4;
        float4 v = *(const float4*)&xrow[c];
        bf16x4 o; o[0]=(__bf16)v.x; o[1]=(__bf16)v.y; o[2]=(__bf16)v.z; o[3]=(__bf16)v.w;
        *(bf16x4*)&xbrow[c] = o;
#pragma unroll
        for (int e = 0; e < NEXP; ++e) {
            float4 g = *(const float4*)&gw[e * DIM + c];
            part[e] += v.x*g.x + v.y*g.y + v.z*g.z + v.w*g.w;
        }
    }
#pragma unroll
    for (int off = 32; off > 0; off >>= 1) {
#pragma unroll
        for (int e = 0; e < NEXP; ++e) part[e] += __shfl_xor(part[e], off);
    }
    if (lane == 0) {
        int k = topk_p[0];
        if (k < 1) k = 1;
        if (k > NEXP) k = NEXP;
        float p[NEXP];
        float mx = -1e30f;
#pragma unroll
        for (int e = 0; e < NEXP; ++e) {
            p[e] = part[e] + gb[e];
            mx = fmaxf(mx, p[e]);
        }
#pragma unroll
        for (int e = 0; e < NEXP; ++e) p[e] = __expf(p[e] - mx);
        bool used[NEXP];
#pragma unroll
        for (int e = 0; e < NEXP; ++e) used[e] = false;
        int sel[NEXP]; float selp[NEXP]; float wsum = 0.f;
        for (int j = 0; j < k; ++j) {
            int best = 0; float bv = -1.f;
            for (int e = 0; e < NEXP; ++e)
                if (!used[e] && p[e] > bv) { bv = p[e]; best = e; }  // ties->low idx
            used[best] = true; sel[j] = best; selp[j] = bv; wsum += bv;
        }
        for (int j = 0; j < k; ++j) {
            int e = sel[j];
            int pos = atomicAdd(&counts[e], 1);
            bucket[e * T_TOK + pos]  = t;
            bweight[e * T_TOK + pos] = selp[j] / wsum;
        }
    }
}

// Per-expert transpose+convert: in [z][R][C] fp32 -> out [z][C][R] bf16.
__global__ __launch_bounds__(256)
void transpose_cvt(const float* __restrict__ in, __bf16* __restrict__ out,
                   int R, int C) {
    const size_t zo = (size_t)blockIdx.z * R * C;
    in += zo; out += zo;
    __shared__ float ts[64][65];
    const int c0 = blockIdx.x * 64, r0 = blockIdx.y * 64;
    const int t = threadIdx.x;
    const int rr = t >> 2, cc4 = (t & 3) * 16;
    const float* src = in + (size_t)(r0 + rr) * C + c0 + cc4;
#pragma unroll
    for (int i = 0; i < 4; ++i) {
        float4 v = *(const float4*)(src + i * 4);
        ts[rr][cc4 + i*4 + 0] = v.x; ts[rr][cc4 + i*4 + 1] = v.y;
        ts[rr][cc4 + i*4 + 2] = v.z; ts[rr][cc4 + i*4 + 3] = v.w;
    }
    __syncthreads();
    const int oc = rr, orc = cc4;
    bf16x8 o0, o1;
#pragma unroll
    for (int i = 0; i < 8; ++i) o0[i] = (__bf16)ts[orc + i][oc];
#pragma unroll
    for (int i = 0; i < 8; ++i) o1[i] = (__bf16)ts[orc + 8 + i][oc];
    __bf16* dst = out + (size_t)(c0 + oc) * R + r0 + orc;
    *(bf16x8*)dst = o0;
    *(bf16x8*)(dst + 8) = o1;
}

// ---------------------------------------------------------------------------
// Work list: (e, tile256) entries; hdr[0]=n, entries at hdr+8.
// ---------------------------------------------------------------------------
__global__ __launch_bounds__(64)
void build_work(const int* __restrict__ counts, int* __restrict__ hdr) {
    __shared__ int off1[NEXP + 1];
    const int lane = threadIdx.x;
    if (lane == 0) {
        int a = 0;
        for (int e = 0; e < NEXP; ++e) {
            off1[e] = a;
            a += (counts[e] + 255) >> 8;
        }
        off1[NEXP] = a;
        hdr[0] = a;
    }
    __syncthreads();
    for (int e = 0; e < NEXP; ++e) {
        int n1 = off1[e + 1] - off1[e];
        for (int j = lane; j < n1; j += 64) hdr[8 + off1[e] + j] = (e << 16) | j;
    }
}

// ---------------------------------------------------------------------------
// Shared GEMM geometry: tile 256x256, BK=32, 8 waves (2M x 4N).
// LDS: 4 buffers x (A[256][32] 16KB | B[256][32] 16KB) = 128KB.
// Row = 64B; T2 swizzle: 16B slot s of row r holds global chunk s^((r>>1)&3)
// (realized by inverse-swizzling the glds16 SOURCE; LDS dest stays linear).
// Pipeline: stage tile t+3, s_waitcnt vmcnt(12) (tile t landed, 12 in
// flight), s_barrier, 12x asm ds_read_b128, lgkmcnt(0)+sched_barrier,
// 32 MFMA (setprio), s_barrier.
// ---------------------------------------------------------------------------

// ---------------------------------------------------------------------------
// GEMM1: H[e,pos,f] = silu( xb[tok].W1T[e][f][:] + b1[e][f] )
// ---------------------------------------------------------------------------
__global__ __launch_bounds__(512, 2)
void moe_gemm1(const __bf16* __restrict__ xb,
               const __bf16* __restrict__ w1t,   // [E][F][D]
               const float*  __restrict__ b1,
               const int*    __restrict__ counts,
               const int*    __restrict__ bucket,
               const int*    __restrict__ hdr,
               __bf16* __restrict__ H) {
    __shared__ __align__(16) char sb[4 * 32768];   // 128KB pipeline buffers
    __shared__ int tok_s[256];
    const int tid = threadIdx.x;
    const int wave = tid >> 6, lane = tid & 63;
    const int wm = wave & 1, wn = wave >> 1;        // 2 x 4 wave grid
    const int quad = lane >> 4, l15 = lane & 15;
    const int lrow = lane >> 2;
    const int rr  = tid >> 2;                       // staging row 0..127
    const int srh = ((tid & 3) ^ ((tid >> 3) & 3)) * 8;   // inverse-swz src elems
    const int swz16 = (((lane >> 4) ^ ((lane >> 1) & 3)) << 4);
    const int aoff = (wm * 128 + l15) * 64 + swz16;
    const int boff = 16384 + (wn * 64 + l15) * 64 + swz16;
    lds3 s3 = (lds3)sb;

    const int NT = DIM / 32;   // 32 K-tiles
    const int n1 = hdr[0];
    const int total = n1 * (FDIM / 256);
    for (int phys = blockIdx.x; phys < total; phys += gridDim.x) {
        const int u = xcd_swz(phys, total);
        const int entry = hdr[8 + (u % n1)];
        const int e = entry >> 16, tile = entry & 0xffff;
        const int nb = (u / n1) * 256;
        const int cnt = counts[e];
        for (int r = tid; r < 256; r += 512) {
            int rw = tile * 256 + r;
            if (rw >= cnt) rw = cnt - 1;
            tok_s[r] = bucket[e * T_TOK + rw];
        }
        __syncthreads();   // drains vmcnt to 0 -> clean counting

        const __bf16* pa0 = xb + (size_t)tok_s[rr]       * DIM + srh;
        const __bf16* pa1 = xb + (size_t)tok_s[rr + 128] * DIM + srh;
        const __bf16* pb0 = w1t + ((size_t)e * FDIM + nb + rr) * DIM + srh;
        const __bf16* pb1 = pb0 + (size_t)128 * DIM;

        f32x4 acc[8][4];
#pragma unroll
        for (int i = 0; i < 8; ++i)
#pragma unroll
            for (int j = 0; j < 4; ++j) acc[i][j] = (f32x4){0.f,0.f,0.f,0.f};

        // prologue: stage tiles 0..2 into buffers 0..2
#pragma unroll
        for (int p = 0; p < 3; ++p) {
            char* db = sb + p * 32768;
            const int ko = p * 32;
            glds16(pa0 + ko, db + wave * 1024);
            glds16(pa1 + ko, db + 8192 + wave * 1024);
            glds16(pb0 + ko, db + 16384 + wave * 1024);
            glds16(pb1 + ko, db + 24576 + wave * 1024);
        }

#pragma unroll 1
        for (int t = 0; t < NT; ++t) {
            const int bc = t & 3;
            if (t + 3 < NT) {
                char* db = sb + ((t + 3) & 3) * 32768;
                const int ko = (t + 3) * 32;
                glds16(pa0 + ko, db + wave * 1024);
                glds16(pa1 + ko, db + 8192 + wave * 1024);
                glds16(pb0 + ko, db + 16384 + wave * 1024);
                glds16(pb1 + ko, db + 24576 + wave * 1024);
                asm volatile("s_waitcnt vmcnt(12)" ::: "memory");
            } else if (t + 3 == NT) {
                asm volatile("s_waitcnt vmcnt(8)" ::: "memory");
            } else if (t + 2 == NT) {
                asm volatile("s_waitcnt vmcnt(4)" ::: "memory");
            } else {
                asm volatile("s_waitcnt vmcnt(0)" ::: "memory");
            }
            __builtin_amdgcn_s_barrier();

            lds3 a3 = s3 + bc * 32768 + aoff;
            lds3 b3 = s3 + bc * 32768 + boff;
            bf16x8 af[8], bfr[4];
            DSR(af[0], a3, 0);    DSR(af[1], a3, 1024);
            DSR(af[2], a3, 2048); DSR(af[3], a3, 3072);
            DSR(af[4], a3, 4096); DSR(af[5], a3, 5120);
            DSR(af[6], a3, 6144); DSR(af[7], a3, 7168);
            DSR(bfr[0], b3, 0);    DSR(bfr[1], b3, 1024);
            DSR(bfr[2], b3, 2048); DSR(bfr[3], b3, 3072);
            asm volatile("s_waitcnt lgkmcnt(0)" ::: "memory");
            __builtin_amdgcn_sched_barrier(0);

            __builtin_amdgcn_s_setprio(1);
#pragma unroll
            for (int i = 0; i < 8; ++i)
#pragma unroll
                for (int j = 0; j < 4; ++j)
                    acc[i][j] = __builtin_amdgcn_mfma_f32_16x16x32_bf16(
                        af[i], bfr[j], acc[i][j], 0, 0, 0);
            __builtin_amdgcn_s_setprio(0);
            __builtin_amdgcn_s_barrier();
        }

        // Epilogue: wave-private LDS transpose (stride 72, 16B-aligned)
        // -> b128 H stores.
        __bf16* stg = (__bf16*)(sb + wave * 2304);
        const float* b1e = b1 + e * FDIM + nb + wn * 64;
#pragma unroll
        for (int i = 0; i < 8; ++i) {
#pragma unroll
            for (int j = 0; j < 4; ++j) {
                float bias = b1e[j * 16 + l15];
#pragma unroll
                for (int r = 0; r < 4; ++r) {
                    float v = acc[i][j][r] + bias;
                    float s = v / (1.f + __expf(-v));   // silu
                    stg[(quad*4 + r) * 72 + j*16 + l15] = (__bf16)s;
                }
            }
            int prow = tile * 256 + wm * 128 + i * 16 + lrow;
            if (prow < cnt) {
                bf16x8 v0 = *(const bf16x8*)&stg[lrow * 72 + (lane & 3) * 16];
                bf16x8 v1 = *(const bf16x8*)&stg[lrow * 72 + (lane & 3) * 16 + 8];
                __bf16* dst = H + (size_t)(e * T_TOK + prow) * FDIM
                              + nb + wn * 64 + (lane & 3) * 16;
                *(bf16x8*)dst = v0;
                *(bf16x8*)(dst + 8) = v1;
            }
        }
        __syncthreads();   // protect smem/tok_s before next unit
    }
}

// ---------------------------------------------------------------------------
// GEMM2: out[tok,d] += w * ( H[e,pos,:].W2T[e][d][:] + b2[e][d] )
// split-K x2 (each block reduces FDIM/2 = 2048).
// ---------------------------------------------------------------------------
#define KSPLIT 2
#define KHALF  (FDIM / KSPLIT)

__global__ __launch_bounds__(512, 2)
void moe_gemm2(const __bf16* __restrict__ H,
               const __bf16* __restrict__ w2t,   // [E][D][F]
               const float*  __restrict__ b2,
               const int*    __restrict__ counts,
               const int*    __restrict__ bucket,
               const float*  __restrict__ bweight,
               const int*    __restrict__ hdr,
               float* __restrict__ out) {
    __shared__ __align__(16) char sb[4 * 32768];
    __shared__ int   tok_s[256];
    __shared__ float w_s[256];
    const int tid = threadIdx.x;
    const int wave = tid >> 6, lane = tid & 63;
    const int wm = wave & 1, wn = wave >> 1;
    const int quad = lane >> 4, l15 = lane & 15;
    const int rr  = tid >> 2;
    const int srh = ((tid & 3) ^ ((tid >> 3) & 3)) * 8;
    const int swz16 = (((lane >> 4) ^ ((lane >> 1) & 3)) << 4);
    const int aoff = (wm * 128 + l15) * 64 + swz16;
    const int boff = 16384 + (wn * 64 + l15) * 64 + swz16;
    lds3 s3 = (lds3)sb;

    const int NT = KHALF / 32;   // 64 K-tiles
    const int n1 = hdr[0];
    const int total = n1 * (DIM / 256) * KSPLIT;
    for (int phys = blockIdx.x; phys < total; phys += gridDim.x) {
        const int u = xcd_swz(phys, total);
        const int entry = hdr[8 + (u % n1)];
        const int e = entry >> 16, tile = entry & 0xffff;
        const int rest = u / n1;
        const int nb = (rest & 3) * 256;       // DIM/256 = 4 output blocks
        const int kc = rest >> 2;              // split-K chunk: 0 or 1
        const int cnt = counts[e];
        for (int r = tid; r < 256; r += 512) {
            int rw = tile * 256 + r;
            int rc = rw < cnt ? rw : cnt - 1;
            tok_s[r] = bucket[e * T_TOK + rc];
            w_s[r]   = bweight[e * T_TOK + rc];
        }
        __syncthreads();

        const size_t kbase = (size_t)kc * KHALF;
        // A rows (H) are contiguous positions — no gather needed.
        const __bf16* pa0 = H + (size_t)(e * T_TOK + tile * 256 + rr) * FDIM + kbase + srh;
        const __bf16* pa1 = pa0 + (size_t)128 * FDIM;
        const __bf16* pb0 = w2t + ((size_t)e * DIM + nb + rr) * FDIM + kbase + srh;
        const __bf16* pb1 = pb0 + (size_t)128 * FDIM;

        f32x4 acc[8][4];
#pragma unroll
        for (int i = 0; i < 8; ++i)
#pragma unroll
            for (int j = 0; j < 4; ++j) acc[i][j] = (f32x4){0.f,0.f,0.f,0.f};

#pragma unroll
        for (int p = 0; p < 3; ++p) {
            char* db = sb + p * 32768;
            const int ko = p * 32;
            glds16(pa0 + ko, db + wave * 1024);
            glds16(pa1 + ko, db + 8192 + wave * 1024);
            glds16(pb0 + ko, db + 16384 + wave * 1024);
            glds16(pb1 + ko, db + 24576 + wave * 1024);
        }

#pragma unroll 1
        for (int t = 0; t < NT; ++t) {
            const int bc = t & 3;
            if (t + 3 < NT) {
                char* db = sb + ((t + 3) & 3) * 32768;
                const int ko = (t + 3) * 32;
                glds16(pa0 + ko, db + wave * 1024);
                glds16(pa1 + ko, db + 8192 + wave * 1024);
                glds16(pb0 + ko, db + 16384 + wave * 1024);
                glds16(pb1 + ko, db + 24576 + wave * 1024);
                asm volatile("s_waitcnt vmcnt(12)" ::: "memory");
            } else if (t + 3 == NT) {
                asm volatile("s_waitcnt vmcnt(8)" ::: "memory");
            } else if (t + 2 == NT) {
                asm volatile("s_waitcnt vmcnt(4)" ::: "memory");
            } else {
                asm volatile("s_waitcnt vmcnt(0)" ::: "memory");
            }
            __builtin_amdgcn_s_barrier();

            lds3 a3 = s3 + bc * 32768 + aoff;
            lds3 b3 = s3 + bc * 32768 + boff;
            bf16x8 af[8], bfr[4];
            DSR(af[0], a3, 0);    DSR(af[1], a3, 1024);
            DSR(af[2], a3, 2048); DSR(af[3], a3, 3072);
            DSR(af[4], a3, 4096); DSR(af[5], a3, 5120);
            DSR(af[6], a3, 6144); DSR(af[7], a3, 7168);
            DSR(bfr[0], b3, 0);    DSR(bfr[1], b3, 1024);
            DSR(bfr[2], b3, 2048); DSR(bfr[3], b3, 3072);
            asm volatile("s_waitcnt lgkmcnt(0)" ::: "memory");
            __builtin_amdgcn_sched_barrier(0);

            __builtin_amdgcn_s_setprio(1);
#pragma unroll
            for (int i = 0; i < 8; ++i)
#pragma unroll
                for (int j = 0; j < 4; ++j)
                    acc[i][j] = __builtin_amdgcn_mfma_f32_16x16x32_bf16(
                        af[i], bfr[j], acc[i][j], 0, 0, 0);
            __builtin_amdgcn_s_setprio(0);
            __builtin_amdgcn_s_barrier();
        }

        float bias[4];
#pragma unroll
        for (int j = 0; j < 4; ++j)
            bias[j] = (kc == 0) ? b2[e * DIM + nb + wn * 64 + j * 16 + l15] : 0.f;
#pragma unroll
        for (int i = 0; i < 8; ++i)
#pragma unroll
            for (int j = 0; j < 4; ++j)
#pragma unroll
                for (int r = 0; r < 4; ++r) {
                    int m = wm * 128 + i * 16 + quad * 4 + r;
                    int prow = tile * 256 + m;
                    if (prow < cnt) {
                        int dc = nb + wn * 64 + j * 16 + l15;
                        float v = acc[i][j][r] + bias[j];
                        atomicAdd(&out[(size_t)tok_s[m] * DIM + dc], w_s[m] * v);
                    }
                }
        __syncthreads();   // protect tok_s/w_s before next unit
    }
}

extern "C" void kernel_launch(void* const* d_in, const int* in_sizes, int n_in,
                              void* d_out, int out_size, void* d_ws, size_t ws_size,
                              hipStream_t stream) {
    const float* x  = (const float*)d_in[0];
    const float* gw = (const float*)d_in[1];
    const float* gb = (const float*)d_in[2];
    const float* w1 = (const float*)d_in[3];
    const float* b1 = (const float*)d_in[4];
    const float* w2 = (const float*)d_in[5];
    const float* b2 = (const float*)d_in[6];
    const int* topk = (const int*)d_in[7];
    float* out = (float*)d_out;

    char* ws = (char*)d_ws;
    size_t off = 0;
    int* counts = (int*)(ws + off);    off += 256;
    int* bucket = (int*)(ws + off);    off += (size_t)NEXP * T_TOK * 4;
    float* bw   = (float*)(ws + off);  off += (size_t)NEXP * T_TOK * 4;
    int* hdr    = (int*)(ws + off);    off += 4096;
    off = (off + 255) & ~(size_t)255;
    __bf16* xb  = (__bf16*)(ws + off); off += (size_t)T_TOK * DIM * 2;        // 8MB
    __bf16* w1t = (__bf16*)(ws + off); off += (size_t)NEXP * DIM * FDIM * 2;  // 64MB
    __bf16* w2t = (__bf16*)(ws + off); off += (size_t)NEXP * FDIM * DIM * 2;  // 64MB
    __bf16* H   = (__bf16*)(ws + off);                                        // 256MB

    hipMemsetAsync(counts, 0, 256, stream);
    hipMemsetAsync(out, 0, (size_t)out_size * 4, stream);

    moe_router<<<T_TOK, 64, 0, stream>>>(x, gw, gb, topk, counts, bucket, bw, xb);
    transpose_cvt<<<dim3(FDIM/64, DIM/64, NEXP), 256, 0, stream>>>(w1, w1t, DIM, FDIM);
    transpose_cvt<<<dim3(DIM/64, FDIM/64, NEXP), 256, 0, stream>>>(w2, w2t, FDIM, DIM);
    build_work<<<1, 64, 0, stream>>>(counts, hdr);

    moe_gemm1<<<256, 512, 0, stream>>>(xb, w1t, b1, counts, bucket, hdr, H);
    moe_gemm2<<<256, 512, 0, stream>>>(H, w2t, b2, counts, bucket, bw, hdr, out);
}

// Round 4
// 739.797 us; speedup vs baseline: 1.1260x; 1.0434x over previous
//
#include <hip/hip_runtime.h>

// B=2,S=2048 -> T=4096 tokens, D=1024, F=4096, E=8; top_k on device.
// fp32 I/O; bf16 MFMA compute (fp32 accumulate).
// R9: R8 + DSR asm WITHOUT "memory" clobber (SIInsertWaitcnts no longer
// flushes vmcnt(0) before each ds_read -> counted vmcnt(12) pipeline is
// real), sched_barrier after MFMA cluster, bigger grids for tail backfill.
#define T_TOK 4096
#define DIM   1024
#define FDIM  4096
#define NEXP  8

typedef __bf16 bf16x8 __attribute__((ext_vector_type(8)));
typedef __bf16 bf16x4 __attribute__((ext_vector_type(4)));
typedef float  f32x4  __attribute__((ext_vector_type(4)));
typedef const __attribute__((address_space(3))) char* lds3;

__device__ __forceinline__ void glds16(const void* g, void* l) {
    __builtin_amdgcn_global_load_lds(
        (const __attribute__((address_space(1))) void*)g,
        (__attribute__((address_space(3))) void*)l, 16, 0, 0);
}

// NOTE: no "memory" clobber — ordering vs other volatile asm is program
// order; data ordering enforced manually via lgkmcnt(0)+sched_barrier(0).
#define DSR(dst, a, imm) \
    asm volatile("ds_read_b128 %0, %1 offset:" #imm : "=v"(dst) : "v"(a))

// Bijective XCD-chunking swizzle (m204).
__device__ __forceinline__ int xcd_swz(int phys, int total) {
    int q = total >> 3, r = total & 7;
    int x = phys & 7, i = phys >> 3;
    return (x < r ? x * (q + 1) : r * (q + 1) + (x - r) * q) + i;
}

// ---------------------------------------------------------------------------
// Router (+ x->bf16 convert): one wave per token.
// ---------------------------------------------------------------------------
__global__ __launch_bounds__(64)
void moe_router(const float* __restrict__ x,
                const float* __restrict__ gw,
                const float* __restrict__ gb,
                const int*   __restrict__ topk_p,
                int*   __restrict__ counts,
                int*   __restrict__ bucket,
                float* __restrict__ bweight,
                __bf16* __restrict__ xb) {
    const int t = blockIdx.x;
    const int lane = threadIdx.x;
    float part[NEXP];
#pragma unroll
    for (int e = 0; e < NEXP; ++e) part[e] = 0.f;
    const float* xrow = x + (size_t)t * DIM;
    __bf16* xbrow = xb + (size_t)t * DIM;
#pragma unroll
    for (int r = 0; r < 4; ++r) {
        int c = r * 256 + lane * 4;
        float4 v = *(const float4*)&xrow[c];
        bf16x4 o; o[0]=(__bf16)v.x; o[1]=(__bf16)v.y; o[2]=(__bf16)v.z; o[3]=(__bf16)v.w;
        *(bf16x4*)&xbrow[c] = o;
#pragma unroll
        for (int e = 0; e < NEXP; ++e) {
            float4 g = *(const float4*)&gw[e * DIM + c];
            part[e] += v.x*g.x + v.y*g.y + v.z*g.z + v.w*g.w;
        }
    }
#pragma unroll
    for (int off = 32; off > 0; off >>= 1) {
#pragma unroll
        for (int e = 0; e < NEXP; ++e) part[e] += __shfl_xor(part[e], off);
    }
    if (lane == 0) {
        int k = topk_p[0];
        if (k < 1) k = 1;
        if (k > NEXP) k = NEXP;
        float p[NEXP];
        float mx = -1e30f;
#pragma unroll
        for (int e = 0; e < NEXP; ++e) {
            p[e] = part[e] + gb[e];
            mx = fmaxf(mx, p[e]);
        }
#pragma unroll
        for (int e = 0; e < NEXP; ++e) p[e] = __expf(p[e] - mx);
        bool used[NEXP];
#pragma unroll
        for (int e = 0; e < NEXP; ++e) used[e] = false;
        int sel[NEXP]; float selp[NEXP]; float wsum = 0.f;
        for (int j = 0; j < k; ++j) {
            int best = 0; float bv = -1.f;
            for (int e = 0; e < NEXP; ++e)
                if (!used[e] && p[e] > bv) { bv = p[e]; best = e; }  // ties->low idx
            used[best] = true; sel[j] = best; selp[j] = bv; wsum += bv;
        }
        for (int j = 0; j < k; ++j) {
            int e = sel[j];
            int pos = atomicAdd(&counts[e], 1);
            bucket[e * T_TOK + pos]  = t;
            bweight[e * T_TOK + pos] = selp[j] / wsum;
        }
    }
}

// Per-expert transpose+convert: in [z][R][C] fp32 -> out [z][C][R] bf16.
__global__ __launch_bounds__(256)
void transpose_cvt(const float* __restrict__ in, __bf16* __restrict__ out,
                   int R, int C) {
    const size_t zo = (size_t)blockIdx.z * R * C;
    in += zo; out += zo;
    __shared__ float ts[64][65];
    const int c0 = blockIdx.x * 64, r0 = blockIdx.y * 64;
    const int t = threadIdx.x;
    const int rr = t >> 2, cc4 = (t & 3) * 16;
    const float* src = in + (size_t)(r0 + rr) * C + c0 + cc4;
#pragma unroll
    for (int i = 0; i < 4; ++i) {
        float4 v = *(const float4*)(src + i * 4);
        ts[rr][cc4 + i*4 + 0] = v.x; ts[rr][cc4 + i*4 + 1] = v.y;
        ts[rr][cc4 + i*4 + 2] = v.z; ts[rr][cc4 + i*4 + 3] = v.w;
    }
    __syncthreads();
    const int oc = rr, orc = cc4;
    bf16x8 o0, o1;
#pragma unroll
    for (int i = 0; i < 8; ++i) o0[i] = (__bf16)ts[orc + i][oc];
#pragma unroll
    for (int i = 0; i < 8; ++i) o1[i] = (__bf16)ts[orc + 8 + i][oc];
    __bf16* dst = out + (size_t)(c0 + oc) * R + r0 + orc;
    *(bf16x8*)dst = o0;
    *(bf16x8*)(dst + 8) = o1;
}

// ---------------------------------------------------------------------------
// Work list: (e, tile256) entries; hdr[0]=n, entries at hdr+8.
// ---------------------------------------------------------------------------
__global__ __launch_bounds__(64)
void build_work(const int* __restrict__ counts, int* __restrict__ hdr) {
    __shared__ int off1[NEXP + 1];
    const int lane = threadIdx.x;
    if (lane == 0) {
        int a = 0;
        for (int e = 0; e < NEXP; ++e) {
            off1[e] = a;
            a += (counts[e] + 255) >> 8;
        }
        off1[NEXP] = a;
        hdr[0] = a;
    }
    __syncthreads();
    for (int e = 0; e < NEXP; ++e) {
        int n1 = off1[e + 1] - off1[e];
        for (int j = lane; j < n1; j += 64) hdr[8 + off1[e] + j] = (e << 16) | j;
    }
}

// ---------------------------------------------------------------------------
// Shared GEMM geometry: tile 256x256, BK=32, 8 waves (2M x 4N).
// LDS: 4 buffers x (A[256][32] 16KB | B[256][32] 16KB) = 128KB.
// Row = 64B; T2 swizzle: 16B slot s of row r holds global chunk s^((r>>1)&3)
// (realized by inverse-swizzling the glds16 SOURCE; LDS dest stays linear).
// Pipeline: stage tile t+3, s_waitcnt vmcnt(12) (tile t landed, 12 in
// flight), s_barrier, 12x asm ds_read_b128 (NO memory clobber),
// lgkmcnt(0)+sched_barrier, 32 MFMA (setprio), sched_barrier, s_barrier.
// ---------------------------------------------------------------------------

// ---------------------------------------------------------------------------
// GEMM1: H[e,pos,f] = silu( xb[tok].W1T[e][f][:] + b1[e][f] )
// ---------------------------------------------------------------------------
__global__ __launch_bounds__(512, 2)
void moe_gemm1(const __bf16* __restrict__ xb,
               const __bf16* __restrict__ w1t,   // [E][F][D]
               const float*  __restrict__ b1,
               const int*    __restrict__ counts,
               const int*    __restrict__ bucket,
               const int*    __restrict__ hdr,
               __bf16* __restrict__ H) {
    __shared__ __align__(16) char sb[4 * 32768];   // 128KB pipeline buffers
    __shared__ int tok_s[256];
    const int tid = threadIdx.x;
    const int wave = tid >> 6, lane = tid & 63;
    const int wm = wave & 1, wn = wave >> 1;        // 2 x 4 wave grid
    const int quad = lane >> 4, l15 = lane & 15;
    const int lrow = lane >> 2;
    const int rr  = tid >> 2;                       // staging row 0..127
    const int srh = ((tid & 3) ^ ((tid >> 3) & 3)) * 8;   // inverse-swz src elems
    const int swz16 = (((lane >> 4) ^ ((lane >> 1) & 3)) << 4);
    const int aoff = (wm * 128 + l15) * 64 + swz16;
    const int boff = 16384 + (wn * 64 + l15) * 64 + swz16;
    lds3 s3 = (lds3)sb;

    const int NT = DIM / 32;   // 32 K-tiles
    const int n1 = hdr[0];
    const int total = n1 * (FDIM / 256);
    for (int phys = blockIdx.x; phys < total; phys += gridDim.x) {
        const int u = xcd_swz(phys, total);
        const int entry = hdr[8 + (u % n1)];
        const int e = entry >> 16, tile = entry & 0xffff;
        const int nb = (u / n1) * 256;
        const int cnt = counts[e];
        for (int r = tid; r < 256; r += 512) {
            int rw = tile * 256 + r;
            if (rw >= cnt) rw = cnt - 1;
            tok_s[r] = bucket[e * T_TOK + rw];
        }
        __syncthreads();   // drains vmcnt to 0 -> clean counting

        const __bf16* pa0 = xb + (size_t)tok_s[rr]       * DIM + srh;
        const __bf16* pa1 = xb + (size_t)tok_s[rr + 128] * DIM + srh;
        const __bf16* pb0 = w1t + ((size_t)e * FDIM + nb + rr) * DIM + srh;
        const __bf16* pb1 = pb0 + (size_t)128 * DIM;

        f32x4 acc[8][4];
#pragma unroll
        for (int i = 0; i < 8; ++i)
#pragma unroll
            for (int j = 0; j < 4; ++j) acc[i][j] = (f32x4){0.f,0.f,0.f,0.f};

        // prologue: stage tiles 0..2 into buffers 0..2
#pragma unroll
        for (int p = 0; p < 3; ++p) {
            char* db = sb + p * 32768;
            const int ko = p * 32;
            glds16(pa0 + ko, db + wave * 1024);
            glds16(pa1 + ko, db + 8192 + wave * 1024);
            glds16(pb0 + ko, db + 16384 + wave * 1024);
            glds16(pb1 + ko, db + 24576 + wave * 1024);
        }

#pragma unroll 1
        for (int t = 0; t < NT; ++t) {
            const int bc = t & 3;
            if (t + 3 < NT) {
                char* db = sb + ((t + 3) & 3) * 32768;
                const int ko = (t + 3) * 32;
                glds16(pa0 + ko, db + wave * 1024);
                glds16(pa1 + ko, db + 8192 + wave * 1024);
                glds16(pb0 + ko, db + 16384 + wave * 1024);
                glds16(pb1 + ko, db + 24576 + wave * 1024);
                asm volatile("s_waitcnt vmcnt(12)" ::: "memory");
            } else if (t + 3 == NT) {
                asm volatile("s_waitcnt vmcnt(8)" ::: "memory");
            } else if (t + 2 == NT) {
                asm volatile("s_waitcnt vmcnt(4)" ::: "memory");
            } else {
                asm volatile("s_waitcnt vmcnt(0)" ::: "memory");
            }
            __builtin_amdgcn_s_barrier();

            lds3 a3 = s3 + bc * 32768 + aoff;
            lds3 b3 = s3 + bc * 32768 + boff;
            bf16x8 af[8], bfr[4];
            DSR(af[0], a3, 0);    DSR(af[1], a3, 1024);
            DSR(af[2], a3, 2048); DSR(af[3], a3, 3072);
            DSR(af[4], a3, 4096); DSR(af[5], a3, 5120);
            DSR(af[6], a3, 6144); DSR(af[7], a3, 7168);
            DSR(bfr[0], b3, 0);    DSR(bfr[1], b3, 1024);
            DSR(bfr[2], b3, 2048); DSR(bfr[3], b3, 3072);
            asm volatile("s_waitcnt lgkmcnt(0)" ::: "memory");
            __builtin_amdgcn_sched_barrier(0);

            __builtin_amdgcn_s_setprio(1);
#pragma unroll
            for (int i = 0; i < 8; ++i)
#pragma unroll
                for (int j = 0; j < 4; ++j)
                    acc[i][j] = __builtin_amdgcn_mfma_f32_16x16x32_bf16(
                        af[i], bfr[j], acc[i][j], 0, 0, 0);
            __builtin_amdgcn_s_setprio(0);
            __builtin_amdgcn_sched_barrier(0);
            __builtin_amdgcn_s_barrier();
        }

        // Epilogue: wave-private LDS transpose (stride 72, 16B-aligned)
        // -> b128 H stores.
        __bf16* stg = (__bf16*)(sb + wave * 2304);
        const float* b1e = b1 + e * FDIM + nb + wn * 64;
#pragma unroll
        for (int i = 0; i < 8; ++i) {
#pragma unroll
            for (int j = 0; j < 4; ++j) {
                float bias = b1e[j * 16 + l15];
#pragma unroll
                for (int r = 0; r < 4; ++r) {
                    float v = acc[i][j][r] + bias;
                    float s = v / (1.f + __expf(-v));   // silu
                    stg[(quad*4 + r) * 72 + j*16 + l15] = (__bf16)s;
                }
            }
            int prow = tile * 256 + wm * 128 + i * 16 + lrow;
            if (prow < cnt) {
                bf16x8 v0 = *(const bf16x8*)&stg[lrow * 72 + (lane & 3) * 16];
                bf16x8 v1 = *(const bf16x8*)&stg[lrow * 72 + (lane & 3) * 16 + 8];
                __bf16* dst = H + (size_t)(e * T_TOK + prow) * FDIM
                              + nb + wn * 64 + (lane & 3) * 16;
                *(bf16x8*)dst = v0;
                *(bf16x8*)(dst + 8) = v1;
            }
        }
        __syncthreads();   // protect smem/tok_s before next unit
    }
}

// ---------------------------------------------------------------------------
// GEMM2: out[tok,d] += w * ( H[e,pos,:].W2T[e][d][:] + b2[e][d] )
// split-K x2 (each block reduces FDIM/2 = 2048).
// ---------------------------------------------------------------------------
#define KSPLIT 2
#define KHALF  (FDIM / KSPLIT)

__global__ __launch_bounds__(512, 2)
void moe_gemm2(const __bf16* __restrict__ H,
               const __bf16* __restrict__ w2t,   // [E][D][F]
               const float*  __restrict__ b2,
               const int*    __restrict__ counts,
               const int*    __restrict__ bucket,
               const float*  __restrict__ bweight,
               const int*    __restrict__ hdr,
               float* __restrict__ out) {
    __shared__ __align__(16) char sb[4 * 32768];
    __shared__ int   tok_s[256];
    __shared__ float w_s[256];
    const int tid = threadIdx.x;
    const int wave = tid >> 6, lane = tid & 63;
    const int wm = wave & 1, wn = wave >> 1;
    const int quad = lane >> 4, l15 = lane & 15;
    const int rr  = tid >> 2;
    const int srh = ((tid & 3) ^ ((tid >> 3) & 3)) * 8;
    const int swz16 = (((lane >> 4) ^ ((lane >> 1) & 3)) << 4);
    const int aoff = (wm * 128 + l15) * 64 + swz16;
    const int boff = 16384 + (wn * 64 + l15) * 64 + swz16;
    lds3 s3 = (lds3)sb;

    const int NT = KHALF / 32;   // 64 K-tiles
    const int n1 = hdr[0];
    const int total = n1 * (DIM / 256) * KSPLIT;
    for (int phys = blockIdx.x; phys < total; phys += gridDim.x) {
        const int u = xcd_swz(phys, total);
        const int entry = hdr[8 + (u % n1)];
        const int e = entry >> 16, tile = entry & 0xffff;
        const int rest = u / n1;
        const int nb = (rest & 3) * 256;       // DIM/256 = 4 output blocks
        const int kc = rest >> 2;              // split-K chunk: 0 or 1
        const int cnt = counts[e];
        for (int r = tid; r < 256; r += 512) {
            int rw = tile * 256 + r;
            int rc = rw < cnt ? rw : cnt - 1;
            tok_s[r] = bucket[e * T_TOK + rc];
            w_s[r]   = bweight[e * T_TOK + rc];
        }
        __syncthreads();

        const size_t kbase = (size_t)kc * KHALF;
        // A rows (H) are contiguous positions — no gather needed.
        const __bf16* pa0 = H + (size_t)(e * T_TOK + tile * 256 + rr) * FDIM + kbase + srh;
        const __bf16* pa1 = pa0 + (size_t)128 * FDIM;
        const __bf16* pb0 = w2t + ((size_t)e * DIM + nb + rr) * FDIM + kbase + srh;
        const __bf16* pb1 = pb0 + (size_t)128 * FDIM;

        f32x4 acc[8][4];
#pragma unroll
        for (int i = 0; i < 8; ++i)
#pragma unroll
            for (int j = 0; j < 4; ++j) acc[i][j] = (f32x4){0.f,0.f,0.f,0.f};

#pragma unroll
        for (int p = 0; p < 3; ++p) {
            char* db = sb + p * 32768;
            const int ko = p * 32;
            glds16(pa0 + ko, db + wave * 1024);
            glds16(pa1 + ko, db + 8192 + wave * 1024);
            glds16(pb0 + ko, db + 16384 + wave * 1024);
            glds16(pb1 + ko, db + 24576 + wave * 1024);
        }

#pragma unroll 1
        for (int t = 0; t < NT; ++t) {
            const int bc = t & 3;
            if (t + 3 < NT) {
                char* db = sb + ((t + 3) & 3) * 32768;
                const int ko = (t + 3) * 32;
                glds16(pa0 + ko, db + wave * 1024);
                glds16(pa1 + ko, db + 8192 + wave * 1024);
                glds16(pb0 + ko, db + 16384 + wave * 1024);
                glds16(pb1 + ko, db + 24576 + wave * 1024);
                asm volatile("s_waitcnt vmcnt(12)" ::: "memory");
            } else if (t + 3 == NT) {
                asm volatile("s_waitcnt vmcnt(8)" ::: "memory");
            } else if (t + 2 == NT) {
                asm volatile("s_waitcnt vmcnt(4)" ::: "memory");
            } else {
                asm volatile("s_waitcnt vmcnt(0)" ::: "memory");
            }
            __builtin_amdgcn_s_barrier();

            lds3 a3 = s3 + bc * 32768 + aoff;
            lds3 b3 = s3 + bc * 32768 + boff;
            bf16x8 af[8], bfr[4];
            DSR(af[0], a3, 0);    DSR(af[1], a3, 1024);
            DSR(af[2], a3, 2048); DSR(af[3], a3, 3072);
            DSR(af[4], a3, 4096); DSR(af[5], a3, 5120);
            DSR(af[6], a3, 6144); DSR(af[7], a3, 7168);
            DSR(bfr[0], b3, 0);    DSR(bfr[1], b3, 1024);
            DSR(bfr[2], b3, 2048); DSR(bfr[3], b3, 3072);
            asm volatile("s_waitcnt lgkmcnt(0)" ::: "memory");
            __builtin_amdgcn_sched_barrier(0);

            __builtin_amdgcn_s_setprio(1);
#pragma unroll
            for (int i = 0; i < 8; ++i)
#pragma unroll
                for (int j = 0; j < 4; ++j)
                    acc[i][j] = __builtin_amdgcn_mfma_f32_16x16x32_bf16(
                        af[i], bfr[j], acc[i][j], 0, 0, 0);
            __builtin_amdgcn_s_setprio(0);
            __builtin_amdgcn_sched_barrier(0);
            __builtin_amdgcn_s_barrier();
        }

        float bias[4];
#pragma unroll
        for (int j = 0; j < 4; ++j)
            bias[j] = (kc == 0) ? b2[e * DIM + nb + wn * 64 + j * 16 + l15] : 0.f;
#pragma unroll
        for (int i = 0; i < 8; ++i)
#pragma unroll
            for (int j = 0; j < 4; ++j)
#pragma unroll
                for (int r = 0; r < 4; ++r) {
                    int m = wm * 128 + i * 16 + quad * 4 + r;
                    int prow = tile * 256 + m;
                    if (prow < cnt) {
                        int dc = nb + wn * 64 + j * 16 + l15;
                        float v = acc[i][j][r] + bias[j];
                        atomicAdd(&out[(size_t)tok_s[m] * DIM + dc], w_s[m] * v);
                    }
                }
        __syncthreads();   // protect tok_s/w_s before next unit
    }
}

extern "C" void kernel_launch(void* const* d_in, const int* in_sizes, int n_in,
                              void* d_out, int out_size, void* d_ws, size_t ws_size,
                              hipStream_t stream) {
    const float* x  = (const float*)d_in[0];
    const float* gw = (const float*)d_in[1];
    const float* gb = (const float*)d_in[2];
    const float* w1 = (const float*)d_in[3];
    const float* b1 = (const float*)d_in[4];
    const float* w2 = (const float*)d_in[5];
    const float* b2 = (const float*)d_in[6];
    const int* topk = (const int*)d_in[7];
    float* out = (float*)d_out;

    char* ws = (char*)d_ws;
    size_t off = 0;
    int* counts = (int*)(ws + off);    off += 256;
    int* bucket = (int*)(ws + off);    off += (size_t)NEXP * T_TOK * 4;
    float* bw   = (float*)(ws + off);  off += (size_t)NEXP * T_TOK * 4;
    int* hdr    = (int*)(ws + off);    off += 4096;
    off = (off + 255) & ~(size_t)255;
    __bf16* xb  = (__bf16*)(ws + off); off += (size_t)T_TOK * DIM * 2;        // 8MB
    __bf16* w1t = (__bf16*)(ws + off); off += (size_t)NEXP * DIM * FDIM * 2;  // 64MB
    __bf16* w2t = (__bf16*)(ws + off); off += (size_t)NEXP * FDIM * DIM * 2;  // 64MB
    __bf16* H   = (__bf16*)(ws + off);                                        // 256MB

    hipMemsetAsync(counts, 0, 256, stream);
    hipMemsetAsync(out, 0, (size_t)out_size * 4, stream);

    moe_router<<<T_TOK, 64, 0, stream>>>(x, gw, gb, topk, counts, bucket, bw, xb);
    transpose_cvt<<<dim3(FDIM/64, DIM/64, NEXP), 256, 0, stream>>>(w1, w1t, DIM, FDIM);
    transpose_cvt<<<dim3(DIM/64, FDIM/64, NEXP), 256, 0, stream>>>(w2, w2t, FDIM, DIM);
    build_work<<<1, 64, 0, stream>>>(counts, hdr);

    moe_gemm1<<<1024, 512, 0, stream>>>(xb, w1t, b1, counts, bucket, hdr, H);
    moe_gemm2<<<512, 512, 0, stream>>>(H, w2t, b2, counts, bucket, bw, hdr, out);
}